// Round 6
// baseline (676.063 us; speedup 1.0000x reference)
//
#include <hip/hip_runtime.h>

typedef unsigned short u16;
using bf16x8 = __attribute__((ext_vector_type(8))) short;
using f32x16 = __attribute__((ext_vector_type(16))) float;

#define CH   1024
#define NP   2048
#define CQ   128

__device__ __forceinline__ float bf2f(u16 u){
  union { unsigned u; float f; } c; c.u = ((unsigned)u) << 16; return c.f;
}
__device__ __forceinline__ u16 f2bf(float f){
  unsigned x = __float_as_uint(f);
  unsigned r = (x + 0x7fffu + ((x >> 16) & 1u)) >> 16;
  return (u16)r;
}

__device__ __forceinline__ void gl2lds16(const u16* g, u16* l){
  __builtin_amdgcn_global_load_lds(
      (const __attribute__((address_space(1))) unsigned int*)(const void*)g,
      (__attribute__((address_space(3))) unsigned int*)(void*)l,
      16, 0, 0);
}

__global__ void ws_marker(float* out, float have_mb){
  out[0] = 1048576.0f + have_mb;
}

// ---------------------------------------------------------------------------
// Transpose+split: x [b][c][n] fp32 -> xh,xl [b][n][c] bf16 (hi/lo split)
// ---------------------------------------------------------------------------
__global__ __launch_bounds__(256) void transpose_split(const float* __restrict__ x,
                                                       u16* __restrict__ xh,
                                                       u16* __restrict__ xl){
  const int bb = blockIdx.z;
  const int n0 = blockIdx.x * 64, c0 = blockIdx.y * 64;
  __shared__ float tile[64][65];
  const int t = threadIdx.x;
  const float* xb = x + ((size_t)bb*CH + c0)*NP + n0;
#pragma unroll
  for (int rr = 0; rr < 4; ++rr){
    const int c_l = (t >> 4) + rr*16;
    const int n_l = (t & 15) * 4;
    float4 v = *(const float4*)&xb[(size_t)c_l*NP + n_l];
    tile[c_l][n_l+0] = v.x; tile[c_l][n_l+1] = v.y;
    tile[c_l][n_l+2] = v.z; tile[c_l][n_l+3] = v.w;
  }
  __syncthreads();
  u16* oh = xh + ((size_t)bb*NP + n0)*CH + c0;
  u16* ol = xl + ((size_t)bb*NP + n0)*CH + c0;
#pragma unroll
  for (int rr = 0; rr < 4; ++rr){
    const int n_l = (t >> 4) + rr*16;
    const int c_l = (t & 15) * 4;
    ushort4 h, l;
    float v0 = tile[c_l+0][n_l], v1 = tile[c_l+1][n_l];
    float v2 = tile[c_l+2][n_l], v3 = tile[c_l+3][n_l];
    h.x = f2bf(v0); l.x = f2bf(v0 - bf2f(h.x));
    h.y = f2bf(v1); l.y = f2bf(v1 - bf2f(h.y));
    h.z = f2bf(v2); l.z = f2bf(v2 - bf2f(h.z));
    h.w = f2bf(v3); l.w = f2bf(v3 - bf2f(h.w));
    *(ushort4*)&oh[(size_t)n_l*CH + c_l] = h;
    *(ushort4*)&ol[(size_t)n_l*CH + c_l] = l;
  }
}

// ---------------------------------------------------------------------------
// Prep: weight splits (w3/w4 stacked), BN-param concat, colsum zero.
// ---------------------------------------------------------------------------
__global__ __launch_bounds__(256) void prep_all(
    const float* __restrict__ w0, const float* __restrict__ w1,
    const float* __restrict__ w2, const float* __restrict__ w3,
    const float* __restrict__ w4,
    u16* w1h, u16* w1l, u16* w2h,
    u16* w34h, u16* w34l, u16* w5h,
    const float* g3, const float* b3, const float* m3, const float* v3,
    const float* g4, const float* b4, const float* m4, const float* v4,
    float* p34, float* colsum){
  const int seg = blockIdx.y;
  if (seg == 5){
    for (int i = blockIdx.x*blockDim.x + threadIdx.x; i < 1024; i += gridDim.x*blockDim.x){
      const int grp = i >> 8, j = i & 255;
      const float* pa = (grp==0) ? g3 : (grp==1) ? b3 : (grp==2) ? m3 : v3;
      const float* pb = (grp==0) ? g4 : (grp==1) ? b4 : (grp==2) ? m4 : v4;
      p34[i] = (j < 128) ? pa[j] : pb[j-128];
    }
    return;
  }
  if (seg == 6){
    for (int i = blockIdx.x*blockDim.x + threadIdx.x; i < 8*NP; i += gridDim.x*blockDim.x)
      colsum[i] = 0.f;
    return;
  }
  const float* w; u16 *wh, *wl; int n;
  switch (seg){
    case 0:  w = w0; wh = w1h;           wl = w1l;           n = CH*CH; break;
    case 1:  w = w1; wh = w2h;           wl = nullptr;       n = CH*CH; break;
    case 2:  w = w2; wh = w34h;          wl = w34l;          n = CQ*CH; break;
    case 3:  w = w3; wh = w34h + CQ*CH;  wl = w34l + CQ*CH;  n = CQ*CH; break;
    default: w = w4; wh = w5h;           wl = nullptr;       n = CH*CH; break;
  }
  for (int i = blockIdx.x*blockDim.x + threadIdx.x; i < n; i += gridDim.x*blockDim.x){
    float v = w[i];
    u16 h = f2bf(v);
    wh[i] = h;
    if (wl) wl[i] = f2bf(v - bf2f(h));
  }
}

// ---------------------------------------------------------------------------
// Plain bf16 GEMM, BT-form operands, 128x128 tile, BK=64, 32x32x16 MFMA.
// 1-D grid, XCD swizzle: bb = id&7, y fastest within XCD.
// EPI 0: BN+relu (*cinv[row]), bf16 store out[b][col][row]            (conv2)
// EPI 1: t = x1 - acc*rsum[row], bf16 row-major out[b][row][col]      (attn)
// EPI 2: BN+relu + x1 residual, fp32 store out[b][col][row]           (conv5)
// ---------------------------------------------------------------------------
template<int EPI>
__global__ __launch_bounds__(256, 4) void gemm_plain(
    const u16* __restrict__ A, const u16* __restrict__ B,
    int lda, int ldb, long astr, long bstr, int K,
    void* __restrict__ out0, long ostr, int ldo,
    const float* __restrict__ pg, const float* __restrict__ pb,
    const float* __restrict__ pm, const float* __restrict__ pv,
    const u16* __restrict__ x1h, const u16* __restrict__ x1l,
    const float* __restrict__ cinv, const float* __restrict__ rsum)
{
  __shared__ __align__(16) u16 sA[8192], sB[8192];   // 128 rows x 64 k
  const int tid  = threadIdx.x;
  const int lane = tid & 63, wave = tid >> 6;
  const int wr = wave & 1, wc = wave >> 1;
  const int l31 = lane & 31, h = lane >> 5;
  const int id = blockIdx.x;
  const int bb = id & 7;
  const int rest = id >> 3;
  const int by = rest & 7;
  const int bx = rest >> 3;
  const u16* Ab = A + (size_t)bb*astr + (size_t)bx*128*lda;
  const u16* Bb = B + (size_t)bb*bstr + (size_t)by*128*ldb;

  f32x16 acc[2][2] = {};

  const int srow = tid >> 3;
  const int schunk = tid & 7;

  for (int kt = 0; kt < K; kt += 64){
#pragma unroll
    for (int r = 0; r < 4; ++r){
      const int row = r*32 + srow;
      const int gc8 = ((schunk ^ (row & 7)) << 3);
      gl2lds16(Ab + (size_t)row*lda + kt + gc8, &sA[r*2048 + tid*8]);
      gl2lds16(Bb + (size_t)row*ldb + kt + gc8, &sB[r*2048 + tid*8]);
    }
    __syncthreads();
#pragma unroll
    for (int s = 0; s < 4; ++s){
      bf16x8 af[2], bfr[2];
#pragma unroll
      for (int t = 0; t < 2; ++t){
        const int ra = wr*64 + t*32 + l31;
        af[t]  = *(const bf16x8*)&sA[ra*64 + ((((s<<1) + h) ^ (ra & 7)) << 3)];
        const int rb = wc*64 + t*32 + l31;
        bfr[t] = *(const bf16x8*)&sB[rb*64 + ((((s<<1) + h) ^ (rb & 7)) << 3)];
      }
#pragma unroll
      for (int i = 0; i < 2; ++i)
#pragma unroll
        for (int j = 0; j < 2; ++j)
          acc[i][j] = __builtin_amdgcn_mfma_f32_32x32x16_bf16(af[i], bfr[j], acc[i][j], 0, 0, 0);
    }
    __syncthreads();
  }

  const int rbase = bx*128 + wr*64;
  const int cbase = by*128 + wc*64;
#pragma unroll
  for (int j = 0; j < 2; ++j){
    const int gc = cbase + j*32 + l31;
    float scale = 0.f, bias = 0.f;
    if (EPI == 0 || EPI == 2){
      scale = pg[gc] * rsqrtf(pv[gc] + 1e-5f);
      bias  = pb[gc] - pm[gc]*scale;
    }
#pragma unroll
    for (int i = 0; i < 2; ++i){
#pragma unroll
      for (int rg = 0; rg < 4; ++rg){
        const int gr0 = rbase + i*32 + 8*rg + 4*h;
        if (EPI == 0){
          const float4 cv = *(const float4*)&cinv[(size_t)bb*NP + gr0];
          ushort4 pk;
          pk.x = f2bf(fmaxf(acc[i][j][rg*4+0]*scale + bias, 0.f) * cv.x);
          pk.y = f2bf(fmaxf(acc[i][j][rg*4+1]*scale + bias, 0.f) * cv.y);
          pk.z = f2bf(fmaxf(acc[i][j][rg*4+2]*scale + bias, 0.f) * cv.z);
          pk.w = f2bf(fmaxf(acc[i][j][rg*4+3]*scale + bias, 0.f) * cv.w);
          *(ushort4*)&((u16*)out0)[(size_t)bb*ostr + (size_t)gc*ldo + gr0] = pk;
        } else if (EPI == 1){
          const float4 rv = *(const float4*)&rsum[(size_t)bb*NP + gr0];
#pragma unroll
          for (int r = 0; r < 4; ++r){
            const int gr = gr0 + r;
            const size_t idx = (size_t)bb*ostr + (size_t)gr*ldo + gc;
            const float x1v = bf2f(x1h[idx]) + bf2f(x1l[idx]);
            ((u16*)out0)[idx] = f2bf(x1v - acc[i][j][rg*4+r]*(&rv.x)[r]);
          }
        } else {
          float4 o4;
#pragma unroll
          for (int r = 0; r < 4; ++r){
            const int gr = gr0 + r;
            const size_t xidx = (size_t)bb*((size_t)NP*CH) + (size_t)gr*CH + gc;
            const float x2  = fmaxf(acc[i][j][rg*4+r]*scale + bias, 0.f);
            const float x1v = bf2f(x1h[xidx]) + bf2f(x1l[xidx]);
            (&o4.x)[r] = x1v + x2;
          }
          *(float4*)&((float*)out0)[(size_t)bb*ostr + (size_t)gc*ldo + gr0] = o4;
        }
      }
    }
  }
}

// ---------------------------------------------------------------------------
// Split-bf16 GEMM: acc = Ah*Bh + Ah*Bl + Al*Bh. BK=32, 32x32x16 MFMA.
// EPI 0: BN+relu, split bf16 store row-major (conv1 / conv34)
// EPI 1: expS = exp(acc) -> bf16 store + per-column sum atomics (scores)
// ---------------------------------------------------------------------------
template<int EPI>
__global__ __launch_bounds__(256, 4) void gemm_split3(
    const u16* __restrict__ Ah, const u16* __restrict__ Al,
    const u16* __restrict__ Bh, const u16* __restrict__ Bl,
    int lda, int ldb, long astr, long bstr, int K,
    u16* __restrict__ outH, u16* __restrict__ outL,
    long ostr, int ldo,
    const float* __restrict__ pg, const float* __restrict__ pb,
    const float* __restrict__ pm, const float* __restrict__ pv,
    float* __restrict__ colsum, int gymask, int gyshift)
{
  __shared__ __align__(16) u16 sAh[4096], sAl[4096], sBh[4096], sBl[4096];
  const int tid  = threadIdx.x;
  const int lane = tid & 63, wave = tid >> 6;
  const int wr = wave & 1, wc = wave >> 1;
  const int l31 = lane & 31, h = lane >> 5;
  const int id = blockIdx.x;
  const int bb = id & 7;
  const int rest = id >> 3;
  const int by = rest & gymask;
  const int bx = rest >> gyshift;
  const u16* Abh = Ah + (size_t)bb*astr + (size_t)bx*128*lda;
  const u16* Abl = Al + (size_t)bb*astr + (size_t)bx*128*lda;
  const u16* Bbh = Bh + (size_t)bb*bstr + (size_t)by*128*ldb;
  const u16* Bbl = Bl + (size_t)bb*bstr + (size_t)by*128*ldb;

  f32x16 acc[2][2] = {};

  const int r0 = tid >> 2, r1 = r0 + 64;
  const int cs = (((tid & 3) ^ ((r0 >> 1) & 3)) << 3);

  for (int kt = 0; kt < K; kt += 32){
    gl2lds16(Abh + (size_t)r0*lda + kt + cs, &sAh[tid*8]);
    gl2lds16(Abh + (size_t)r1*lda + kt + cs, &sAh[2048 + tid*8]);
    gl2lds16(Abl + (size_t)r0*lda + kt + cs, &sAl[tid*8]);
    gl2lds16(Abl + (size_t)r1*lda + kt + cs, &sAl[2048 + tid*8]);
    gl2lds16(Bbh + (size_t)r0*ldb + kt + cs, &sBh[tid*8]);
    gl2lds16(Bbh + (size_t)r1*ldb + kt + cs, &sBh[2048 + tid*8]);
    gl2lds16(Bbl + (size_t)r0*ldb + kt + cs, &sBl[tid*8]);
    gl2lds16(Bbl + (size_t)r1*ldb + kt + cs, &sBl[2048 + tid*8]);
    __syncthreads();
#pragma unroll
    for (int s = 0; s < 2; ++s){
      bf16x8 ah[2], al[2], bh2[2], bl2[2];
#pragma unroll
      for (int t = 0; t < 2; ++t){
        const int ra = wr*64 + t*32 + l31;
        const int oa = ra*32 + ((((s<<1) + h) ^ ((ra >> 1) & 3)) << 3);
        ah[t] = *(const bf16x8*)&sAh[oa];
        al[t] = *(const bf16x8*)&sAl[oa];
        const int rb = wc*64 + t*32 + l31;
        const int ob = rb*32 + ((((s<<1) + h) ^ ((rb >> 1) & 3)) << 3);
        bh2[t] = *(const bf16x8*)&sBh[ob];
        bl2[t] = *(const bf16x8*)&sBl[ob];
      }
#pragma unroll
      for (int i = 0; i < 2; ++i)
#pragma unroll
        for (int j = 0; j < 2; ++j){
          acc[i][j] = __builtin_amdgcn_mfma_f32_32x32x16_bf16(ah[i], bh2[j], acc[i][j], 0, 0, 0);
          acc[i][j] = __builtin_amdgcn_mfma_f32_32x32x16_bf16(ah[i], bl2[j], acc[i][j], 0, 0, 0);
          acc[i][j] = __builtin_amdgcn_mfma_f32_32x32x16_bf16(al[i], bh2[j], acc[i][j], 0, 0, 0);
        }
    }
    __syncthreads();
  }

  const int rbase = bx*128 + wr*64;
  const int cbase = by*128 + wc*64;

  if constexpr (EPI == 1){
    __shared__ float colpart[128];
    if (tid < 128) colpart[tid] = 0.f;
    __syncthreads();
#pragma unroll
    for (int j = 0; j < 2; ++j){
      const int gc = cbase + j*32 + l31;
      float lsum = 0.f;
#pragma unroll
      for (int i = 0; i < 2; ++i){
#pragma unroll
        for (int rg = 0; rg < 4; ++rg){
          const int gr0 = rbase + i*32 + 8*rg + 4*h;
#pragma unroll
          for (int r = 0; r < 4; ++r){
            const float e = __expf(fminf(acc[i][j][rg*4+r], 85.f));  // scores >= 0
            outH[(size_t)bb*ostr + (size_t)(gr0 + r)*ldo + gc] = f2bf(e);
            lsum += e;
          }
        }
      }
      atomicAdd(&colpart[wc*64 + j*32 + l31], lsum);
    }
    __syncthreads();
    if (tid < 128) atomicAdd(&colsum[(size_t)bb*NP + (size_t)by*128 + tid], colpart[tid]);
  } else {
#pragma unroll
    for (int j = 0; j < 2; ++j){
      const int gc = cbase + j*32 + l31;
      const float scale = pg[gc] * rsqrtf(pv[gc] + 1e-5f);
      const float bias  = pb[gc] - pm[gc]*scale;
#pragma unroll
      for (int i = 0; i < 2; ++i){
#pragma unroll
        for (int rg = 0; rg < 4; ++rg){
          const int gr0 = rbase + i*32 + 8*rg + 4*h;
#pragma unroll
          for (int r = 0; r < 4; ++r){
            const size_t idx = (size_t)bb*ostr + (size_t)(gr0 + r)*ldo + gc;
            const float y = fmaxf(acc[i][j][rg*4+r]*scale + bias, 0.f);
            const u16 hh = f2bf(y);
            outH[idx] = hh;
            outL[idx] = f2bf(y - bf2f(hh));
          }
        }
      }
    }
  }
}

// colinv = 1/colsum
__global__ __launch_bounds__(256) void colinv_k(const float* __restrict__ cs,
                                                float* __restrict__ ci, int n){
  const int i = blockIdx.x*blockDim.x + threadIdx.x;
  if (i < n) ci[i] = 1.0f / cs[i];
}

// rs[m] = 1/(1e-9 + sum_n expS[m][n]*cinv[n]); one wave per row
__global__ __launch_bounds__(256) void rowsum_dot(const u16* __restrict__ expS,
                                                  const float* __restrict__ cinv,
                                                  float* __restrict__ rs){
  const int row  = blockIdx.x*4 + (threadIdx.x >> 6);
  const int lane = threadIdx.x & 63;
  const int b = row >> 11;
  const u16* e = expS + (size_t)row*NP;
  const float* ci = cinv + (size_t)b*NP;
  float s = 0.f;
#pragma unroll
  for (int k = 0; k < 4; ++k){
    const int idx = (k*64 + lane)*8;
    ushort4 a0 = *(const ushort4*)&e[idx];
    ushort4 a1 = *(const ushort4*)&e[idx+4];
    float4 c0 = *(const float4*)&ci[idx];
    float4 c1 = *(const float4*)&ci[idx+4];
    s += bf2f(a0.x)*c0.x + bf2f(a0.y)*c0.y + bf2f(a0.z)*c0.z + bf2f(a0.w)*c0.w
       + bf2f(a1.x)*c1.x + bf2f(a1.y)*c1.y + bf2f(a1.z)*c1.z + bf2f(a1.w)*c1.w;
  }
#pragma unroll
  for (int off2 = 32; off2; off2 >>= 1) s += __shfl_down(s, off2, 64);
  if (lane == 0) rs[row] = 1.f / (1e-9f + s);
}

// ---------------------------------------------------------------------------
extern "C" void kernel_launch(void* const* d_in, const int* in_sizes, int n_in,
                              void* d_out, int out_size, void* d_ws, size_t ws_size,
                              hipStream_t stream){
  const float* x = (const float*)d_in[0];
  const float *W[5], *g[5], *bt[5], *mu[5], *vr[5];
  for (int i = 0; i < 5; ++i){
    W[i]  = (const float*)d_in[1 + 5*i + 0];
    g[i]  = (const float*)d_in[1 + 5*i + 1];
    bt[i] = (const float*)d_in[1 + 5*i + 2];
    mu[i] = (const float*)d_in[1 + 5*i + 3];
    vr[i] = (const float*)d_in[1 + 5*i + 4];
  }

  char* wp = (char*)d_ws;
  size_t off = 0;
  auto take = [&](size_t bytes) -> void* {
    void* p = wp + off;
    off = (off + bytes + 255) & ~(size_t)255;
    return p;
  };
  u16*   xh   = (u16*)take(33554432);   // x^T hi [b][n][c]; reused as v' [b][c][n]
  u16*   xl   = (u16*)take(33554432);   // x^T lo;           reused as t [b][m][c]
  u16*   x1h  = (u16*)take(33554432);
  u16*   x1l  = (u16*)take(33554432);
  u16*   qkh  = (u16*)take(8388608);    // [b][n][256]: cols 0-127=q, 128-255=k
  u16*   qkl  = (u16*)take(8388608);
  float* csum = (float*)take(65536);    // colsum [b][n]
  float* cinv = (float*)take(65536);    // fp32 1/colsum
  float* rs   = (float*)take(65536);    // fp32 1/(1e-9+rowsum)
  u16*   w1h  = (u16*)take(2097152);
  u16*   w1l  = (u16*)take(2097152);
  u16*   w2h  = (u16*)take(2097152);
  u16*   w34h = (u16*)take(524288);     // [256][1024] stacked W3;W4
  u16*   w34l = (u16*)take(524288);
  u16*   w5h  = (u16*)take(2097152);
  float* p34  = (float*)take(4096);     // g34|b34|m34|v34

  if (ws_size < off){
    ws_marker<<<1, 1, 0, stream>>>((float*)d_out, (float)(ws_size >> 20));
    return;
  }

  u16* vh   = xh;            // x dead after conv1
  u16* tt   = xl;
  u16* expS = (u16*)d_out;   // 64 MiB bf16 = d_out exactly; overwritten by conv5

  prep_all<<<dim3(256, 7), 256, 0, stream>>>(
      W[0], W[1], W[2], W[3], W[4],
      w1h, w1l, w2h, w34h, w34l, w5h,
      g[2], bt[2], mu[2], vr[2], g[3], bt[3], mu[3], vr[3],
      p34, csum);

  transpose_split<<<dim3(32,16,8), 256, 0, stream>>>(x, xh, xl);

  // conv1: x1 = cbr(x, W1)  (split precision)   grid 16x8x8
  gemm_split3<0><<<dim3(1024), 256, 0, stream>>>(
      xh, xl, w1h, w1l, CH, CH, (long)NP*CH, 0, CH,
      x1h, x1l, (long)NP*CH, CH, g[0], bt[0], mu[0], vr[0], nullptr, 7, 3);

  // conv3+conv4 fused: qk[b][n][256]             grid 16x2x8
  gemm_split3<0><<<dim3(256), 256, 0, stream>>>(
      x1h, x1l, w34h, w34l, CH, CH, (long)NP*CH, 0, CH,
      qkh, qkl, (long)NP*256, 256, p34, p34+256, p34+512, p34+768, nullptr, 1, 1);

  // scores: expS[b][m][n] = exp(k_m . q_n) bf16 + column sums   grid 16x16x8
  gemm_split3<1><<<dim3(2048), 256, 0, stream>>>(
      qkh + 128, qkl + 128, qkh, qkl, 256, 256, (long)NP*256, (long)NP*256, CQ,
      expS, nullptr, (long)NP*NP, NP,
      nullptr, nullptr, nullptr, nullptr, csum, 15, 4);

  colinv_k<<<dim3(64), 256, 0, stream>>>(csum, cinv, 8*NP);
  rowsum_dot<<<dim3(4096), 256, 0, stream>>>(expS, cinv, rs);

  // conv2: v' = cbr(x1, W2) * cinv[n]  -> vh [b][c][n]
  gemm_plain<0><<<dim3(1024), 256, 0, stream>>>(
      x1h, w2h, CH, CH, (long)NP*CH, 0, CH,
      vh, (long)CH*NP, NP, g[1], bt[1], mu[1], vr[1],
      nullptr, nullptr, cinv, nullptr);

  // attn: acc = expS . v'; t = x1 - acc*rs
  gemm_plain<1><<<dim3(1024), 256, 0, stream>>>(
      expS, vh, NP, NP, (long)NP*NP, (long)CH*NP, NP,
      tt, (long)NP*CH, CH, nullptr, nullptr, nullptr, nullptr,
      x1h, x1l, nullptr, rs);

  // conv5 + residual -> d_out fp32 [b][c][n]
  gemm_plain<2><<<dim3(1024), 256, 0, stream>>>(
      tt, w5h, CH, CH, (long)NP*CH, 0, CH,
      d_out, (long)CH*NP, NP, g[4], bt[4], mu[4], vr[4],
      x1h, x1l, nullptr, nullptr);
}